// Round 6
// baseline (238.777 us; speedup 1.0000x reference)
//
#include <hip/hip_runtime.h>
#include <cstddef>

// SASRec inference. Round 6: k_score store-path fix — accumulator transposed
// through per-wave LDS tile, plain float4 stores (256B/row-group, full lines)
// replacing 64B-granule nontemporal dword stores.

#define NITEMS 200000
#define Bsz 512
#define Ssz 64
#define Dsz 64
#define EPSV 1e-3f
#define NEGV (-4294967295.0f)   // -2^32 + 1

typedef __attribute__((ext_vector_type(8))) short short8;   // 8 bf16
typedef __attribute__((ext_vector_type(4))) float f32x4;

static __device__ __forceinline__ float wsum(float v){
#pragma unroll
  for (int o = 32; o > 0; o >>= 1) v += __shfl_xor(v, o, 64);
  return v;
}
static __device__ __forceinline__ float wmax(float v){
#pragma unroll
  for (int o = 32; o > 0; o >>= 1) v = fmaxf(v, __shfl_xor(v, o, 64));
  return v;
}

// bf16 round-to-nearest-even (finite inputs only)
static __device__ __forceinline__ unsigned short f2b(float f){
  unsigned u = __float_as_uint(f);
  unsigned r = u + 0x7fffu + ((u >> 16) & 1u);
  return (unsigned short)(r >> 16);
}
static __device__ __forceinline__ float b2f(unsigned short h){
  return __uint_as_float(((unsigned)h) << 16);
}

// ---------------------------------------------------------------- embed ----
__global__ __launch_bounds__(256) void k_embed(const int* __restrict__ ids,
    const float* __restrict__ item_emb, const float* __restrict__ pos_emb,
    float* __restrict__ seq){
  int e4 = blockIdx.x * 256 + threadIdx.x;      // float4 index over [B*S][16]
  int d4 = e4 & 15, bs = e4 >> 4, s = bs & 63;
  int id = ids[bs];
  float4 r = make_float4(0.f, 0.f, 0.f, 0.f);
  if (id != NITEMS){
    float4 a = ((const float4*)(item_emb + (size_t)id * 64))[d4];
    float4 p = ((const float4*)(pos_emb + s * 64))[d4];
    r = make_float4(a.x + p.x, a.y + p.y, a.z + p.z, a.w + p.w);
  }
  ((float4*)seq)[e4] = r;
}

// ------------------------------------------------------ fused block layer --
// Write a preloaded 64x64 weight (2 rows k0,k0+1 x 4 cols per thread) into
// LDS as bf16 hi/lo TRANSPOSED (Wt[n][k]) for contiguous B-frag ds_read_b128.
static __device__ __forceinline__ void stage_wr(unsigned short WH[64][72],
    unsigned short WL[64][72], float4 r0, float4 r1, int t){
  __syncthreads();                 // fence previous consumers of WH/WL
  int k0 = (t >> 4) * 2, n0 = (t & 15) * 4;
  float f0[4] = {r0.x, r0.y, r0.z, r0.w}, f1[4] = {r1.x, r1.y, r1.z, r1.w};
#pragma unroll
  for (int j = 0; j < 4; ++j){
    unsigned short h0 = f2b(f0[j]), h1 = f2b(f1[j]);
    unsigned short l0 = f2b(f0[j] - b2f(h0)), l1 = f2b(f1[j] - b2f(h1));
    *(unsigned*)&WH[n0 + j][k0] = (unsigned)h0 | ((unsigned)h1 << 16);
    *(unsigned*)&WL[n0 + j][k0] = (unsigned)l0 | ((unsigned)l1 << 16);
  }
  __syncthreads();
}

// 64x64 GEMM: A (row-major [m][k] hi/lo) x B (transposed [n][k] hi/lo).
// Wave (qb,cb) computes rows qb*16..+15, cols cb*32..+31 (2 tiles).
// 3-term hi/lo split, fp32 accumulate.
static __device__ __forceinline__ void mm64(
    const unsigned short (*__restrict__ Ah)[72], const unsigned short (*__restrict__ Al)[72],
    const unsigned short (*__restrict__ Bh)[72], const unsigned short (*__restrict__ Bl)[72],
    int qb, int cb, int li, int g, f32x4 acc[2]){
  short8 ah[2], al[2];
#pragma unroll
  for (int kc = 0; kc < 2; ++kc){
    ah[kc] = *(const short8*)&Ah[qb*16 + li][kc*32 + g*8];
    al[kc] = *(const short8*)&Al[qb*16 + li][kc*32 + g*8];
  }
#pragma unroll
  for (int nt = 0; nt < 2; ++nt){
    acc[nt] = (f32x4)(0.f);
#pragma unroll
    for (int kc = 0; kc < 2; ++kc){
      short8 bh = *(const short8*)&Bh[cb*32 + nt*16 + li][kc*32 + g*8];
      short8 bl = *(const short8*)&Bl[cb*32 + nt*16 + li][kc*32 + g*8];
      acc[nt] = __builtin_amdgcn_mfma_f32_16x16x32_bf16(ah[kc], bh, acc[nt], 0, 0, 0);
      acc[nt] = __builtin_amdgcn_mfma_f32_16x16x32_bf16(ah[kc], bl, acc[nt], 0, 0, 0);
      acc[nt] = __builtin_amdgcn_mfma_f32_16x16x32_bf16(al[kc], bh, acc[nt], 0, 0, 0);
    }
  }
}

__global__ __launch_bounds__(512) void k_layer(float* __restrict__ seq_g,
    const int* __restrict__ ids,
    const float* __restrict__ ln1g, const float* __restrict__ ln1b,
    const float* __restrict__ Wq, const float* __restrict__ bq,
    const float* __restrict__ Wk, const float* __restrict__ bk,
    const float* __restrict__ Wv, const float* __restrict__ bv,
    const float* __restrict__ ln2g, const float* __restrict__ ln2b,
    const float* __restrict__ W1, const float* __restrict__ b1,
    const float* __restrict__ W2, const float* __restrict__ b2){
  // f32 buffers (pad 68 floats: rows 16B-aligned for float4 stores)
  __shared__ float F0[64][68];   // seq -> scores -> x (attn out)
  __shared__ float F1[64][68];   // xq (LN1 out) -> x2 (LN2 out)
  // bf16 hi/lo buffers, rows padded to 72 shorts (144B, 16B-aligned)
  // U0: seq -> P ; U1: LN1 out -> LN2 out ; U2: Q -> FFN hidden ; U3: K ; U4: V^T
  __shared__ unsigned short UH[5][64][72], UL[5][64][72];
  __shared__ unsigned short WH[64][72], WL[64][72];
  __shared__ float s_msk[64];

  const int t = threadIdx.x;
  const int lane = t & 63, wid = t >> 6;        // 8 waves
  const int li = lane & 15, g = lane >> 4;
  const int qb = wid & 3, cb = wid >> 2;        // wave tile: rows qb*16, cols cb*32
  const int b = blockIdx.x;
  float* seq_b = seq_g + (size_t)b * Ssz * Dsz;

  // ---- preload all 5 weights into VGPRs (latency hidden under phase 0/LN1)
  const float* Ws[5] = {Wq, Wk, Wv, W1, W2};
  const int k0 = (t >> 4) * 2, n0 = (t & 15) * 4;
  float4 wr[10];
#pragma unroll
  for (int m = 0; m < 5; ++m){
    wr[m*2]   = *(const float4*)&Ws[m][k0 * 64 + n0];
    wr[m*2+1] = *(const float4*)&Ws[m][(k0 + 1) * 64 + n0];
  }

  // ---- phase 0: load seq -> F0 (f32) + U0 (bf16 h/l) ----
#pragma unroll
  for (int it = 0; it < 2; ++it){
    int e4 = t + 512 * it;
    int r = e4 >> 4, c = (e4 & 15) * 4;
    float4 v = ((const float4*)seq_b)[e4];
    *(float4*)&F0[r][c] = v;
    float f[4] = {v.x, v.y, v.z, v.w};
#pragma unroll
    for (int j = 0; j < 4; ++j){
      unsigned short h = f2b(f[j]);
      UH[0][r][c + j] = h;
      UL[0][r][c + j] = f2b(f[j] - b2f(h));
    }
  }
  if (t < 64) s_msk[t] = (ids[b * Ssz + t] != NITEMS) ? 1.f : 0.f;
  __syncthreads();

  // ---- LN1: F0 -> F1 (f32) + U1 (bf16 h/l) ----
  for (int r = wid; r < 64; r += 8){
    float x = F0[r][lane];
    float mu = wsum(x) * (1.f / 64.f);
    float dv = x - mu;
    float var = wsum(dv * dv) * (1.f / 64.f);
    float o = dv * (1.f / sqrtf(var + EPSV)) * ln1g[lane] + ln1b[lane];
    F1[r][lane] = o;
    unsigned short h = f2b(o);
    UH[1][r][lane] = h;
    UL[1][r][lane] = f2b(o - b2f(h));
  }
  // (stage_wr's leading barrier fences LN1 writes)

  // ---- Q = LN1 @ Wq + bq -> U2 (row-major) ----
  stage_wr(WH, WL, wr[0], wr[1], t);
  { f32x4 acc[2]; mm64(UH[1], UL[1], WH, WL, qb, cb, li, g, acc);
#pragma unroll
    for (int nt = 0; nt < 2; ++nt){
      int col = cb*32 + nt*16 + li;
      float bb = bq[col];
#pragma unroll
      for (int r4 = 0; r4 < 4; ++r4){
        int row = qb*16 + g*4 + r4;
        float qv = acc[nt][r4] + bb;
        unsigned short h = f2b(qv);
        UH[2][row][col] = h; UL[2][row][col] = f2b(qv - b2f(h));
      }
    }
  }
  // ---- K = seq @ Wk + bk -> U3 (row-major [pos][dh] == B-layout for QK^T) ----
  stage_wr(WH, WL, wr[2], wr[3], t);
  { f32x4 acc[2]; mm64(UH[0], UL[0], WH, WL, qb, cb, li, g, acc);
#pragma unroll
    for (int nt = 0; nt < 2; ++nt){
      int col = cb*32 + nt*16 + li;
      float bb = bk[col];
#pragma unroll
      for (int r4 = 0; r4 < 4; ++r4){
        int row = qb*16 + g*4 + r4;
        float kv = acc[nt][r4] + bb;
        unsigned short h = f2b(kv);
        UH[3][row][col] = h; UL[3][row][col] = f2b(kv - b2f(h));
      }
    }
  }
  // ---- V = seq @ Wv + bv -> U4 TRANSPOSED (Vt[dh][pos] == B-layout for PV) ----
  stage_wr(WH, WL, wr[4], wr[5], t);
  { f32x4 acc[2]; mm64(UH[0], UL[0], WH, WL, qb, cb, li, g, acc);
#pragma unroll
    for (int nt = 0; nt < 2; ++nt){
      int col = cb*32 + nt*16 + li;
      float bb = bv[col];
#pragma unroll
      for (int r4 = 0; r4 < 4; ++r4){
        int row = qb*16 + g*4 + r4;
        float vv = acc[nt][r4] + bb;
        unsigned short h = f2b(vv);
        UH[4][col][row] = h; UL[4][col][row] = f2b(vv - b2f(h));
      }
    }
  }
  __syncthreads();

  // ---- scores = Q @ K^T -> F0 (f32) ----
  { f32x4 acc[2]; mm64(UH[2], UL[2], UH[3], UL[3], qb, cb, li, g, acc);
#pragma unroll
    for (int nt = 0; nt < 2; ++nt){
      int col = cb*32 + nt*16 + li;
#pragma unroll
      for (int r4 = 0; r4 < 4; ++r4)
        F0[qb*16 + g*4 + r4][col] = acc[nt][r4];
    }
  }
  __syncthreads();

  // ---- masked softmax: F0 -> U0 (P, bf16 h/l) ----
  for (int r = wid; r < 64; r += 8){
    float raw = F0[r][lane];
    bool valid = (lane <= r) && (s_msk[lane] != 0.f);
    float sc = valid ? raw * 0.125f : NEGV;
    float m = wmax(sc);
    float e = __expf(sc - m);
    float ssumv = wsum(e);
    float p = (e / ssumv) * s_msk[r];
    unsigned short h = f2b(p);
    UH[0][r][lane] = h;
    UL[0][r][lane] = f2b(p - b2f(h));
  }
  __syncthreads();

  // ---- x = P @ V + xq -> F0 (f32) ----
  { f32x4 acc[2]; mm64(UH[0], UL[0], UH[4], UL[4], qb, cb, li, g, acc);
#pragma unroll
    for (int nt = 0; nt < 2; ++nt){
      int col = cb*32 + nt*16 + li;
#pragma unroll
      for (int r4 = 0; r4 < 4; ++r4){
        int row = qb*16 + g*4 + r4;
        F0[row][col] = acc[nt][r4] + F1[row][col];
      }
    }
  }
  __syncthreads();

  // ---- LN2: F0 -> F1 (f32 residual) + U1 (bf16 h/l) ----
  for (int r = wid; r < 64; r += 8){
    float x = F0[r][lane];
    float mu = wsum(x) * (1.f / 64.f);
    float dv = x - mu;
    float var = wsum(dv * dv) * (1.f / 64.f);
    float o = dv * (1.f / sqrtf(var + EPSV)) * ln2g[lane] + ln2b[lane];
    F1[r][lane] = o;
    unsigned short h = f2b(o);
    UH[1][r][lane] = h;
    UL[1][r][lane] = f2b(o - b2f(h));
  }
  // ---- h = relu(x2 @ W1 + b1) -> U2 ----
  stage_wr(WH, WL, wr[6], wr[7], t);
  { f32x4 acc[2]; mm64(UH[1], UL[1], WH, WL, qb, cb, li, g, acc);
#pragma unroll
    for (int nt = 0; nt < 2; ++nt){
      int col = cb*32 + nt*16 + li;
      float bb = b1[col];
#pragma unroll
      for (int r4 = 0; r4 < 4; ++r4){
        int row = qb*16 + g*4 + r4;
        float hv = fmaxf(acc[nt][r4] + bb, 0.f);
        unsigned short h = f2b(hv);
        UH[2][row][col] = h; UL[2][row][col] = f2b(hv - b2f(h));
      }
    }
  }
  // ---- out = (h @ W2 + b2 + x2) * mask -> global ----
  stage_wr(WH, WL, wr[8], wr[9], t);
  { f32x4 acc[2]; mm64(UH[2], UL[2], WH, WL, qb, cb, li, g, acc);
#pragma unroll
    for (int nt = 0; nt < 2; ++nt){
      int col = cb*32 + nt*16 + li;
      float bb = b2[col];
#pragma unroll
      for (int r4 = 0; r4 < 4; ++r4){
        int row = qb*16 + g*4 + r4;
        seq_b[row*64 + col] = (acc[nt][r4] + bb + F1[row][col]) * s_msk[row];
      }
    }
  }
}

// ------------------------------------------------------------- final LN ----
__global__ __launch_bounds__(64) void k_lnf(const float* __restrict__ seq,
    const float* __restrict__ g, const float* __restrict__ be,
    float* __restrict__ semb){
  int b = blockIdx.x, lane = threadIdx.x;
  float x = seq[(size_t)b * Ssz * Dsz + 63 * 64 + lane];
  float mu = wsum(x) * (1.f / 64.f);
  float dv = x - mu;
  float var = wsum(dv * dv) * (1.f / 64.f);
  semb[b * 64 + lane] = dv * (1.f / sqrtf(var + EPSV)) * g[lane] + be[lane];
}

// --------------------------------------------------------------- scoring ---
// out[b][i] = sum_d E[b][d]*T[i][d], bf16 MFMA hi/lo 3-term split.
// 64-item tile per block (3125 = 200000/64), B-frags in 64 VGPRs.
// C-write: per-wave LDS transpose -> float4 coalesced stores (256B/row-seg).
__global__ __launch_bounds__(256, 4) void k_score(const float* __restrict__ E,
    const float* __restrict__ T, float* __restrict__ out){
  __shared__ float TT[4][16][68];   // per-wave transpose tile (17 KB total)
  const int t = threadIdx.x, lane = t & 63, w = t >> 6;  // 4 waves
  const int li = lane & 15, g = lane >> 4;
  const int i0 = blockIdx.x * 64;

  // B-frags: T rows i0+nt*16+li (always < NITEMS), k = kc*32+g*8..+7
  short8 Bh[8], Bl[8];
#pragma unroll
  for (int nt = 0; nt < 4; ++nt){
    const float4* tp = (const float4*)(T + (size_t)(i0 + nt*16 + li) * 64);
#pragma unroll
    for (int kc = 0; kc < 2; ++kc){
      float4 v0 = tp[kc*8 + g*2];
      float4 v1 = tp[kc*8 + g*2 + 1];
      float f[8] = {v0.x,v0.y,v0.z,v0.w,v1.x,v1.y,v1.z,v1.w};
      short8 h, l;
#pragma unroll
      for (int j = 0; j < 8; ++j){
        unsigned short hh = f2b(f[j]);
        h[j] = (short)hh;
        l[j] = (short)f2b(f[j] - b2f(hh));
      }
      Bh[nt*2 + kc] = h; Bl[nt*2 + kc] = l;
    }
  }

  for (int c = 0; c < 8; ++c){
    int row = c*64 + w*16 + li;
    const float4* ep = (const float4*)(E + (size_t)row * 64);
    short8 Ah[2], Al[2];
#pragma unroll
    for (int kc = 0; kc < 2; ++kc){
      float4 v0 = ep[kc*8 + g*2];
      float4 v1 = ep[kc*8 + g*2 + 1];
      float f[8] = {v0.x,v0.y,v0.z,v0.w,v1.x,v1.y,v1.z,v1.w};
      short8 h, l;
#pragma unroll
      for (int j = 0; j < 8; ++j){
        unsigned short hh = f2b(f[j]);
        h[j] = (short)hh;
        l[j] = (short)f2b(f[j] - b2f(hh));
      }
      Ah[kc] = h; Al[kc] = l;
    }

    f32x4 acc[4];
#pragma unroll
    for (int nt = 0; nt < 4; ++nt) acc[nt] = (f32x4)(0.f);
#pragma unroll
    for (int kc = 0; kc < 2; ++kc){
#pragma unroll
      for (int nt = 0; nt < 4; ++nt)
        acc[nt] = __builtin_amdgcn_mfma_f32_16x16x32_bf16(Ah[kc], Bh[nt*2+kc], acc[nt], 0, 0, 0);
#pragma unroll
      for (int nt = 0; nt < 4; ++nt)
        acc[nt] = __builtin_amdgcn_mfma_f32_16x16x32_bf16(Ah[kc], Bl[nt*2+kc], acc[nt], 0, 0, 0);
#pragma unroll
      for (int nt = 0; nt < 4; ++nt)
        acc[nt] = __builtin_amdgcn_mfma_f32_16x16x32_bf16(Al[kc], Bh[nt*2+kc], acc[nt], 0, 0, 0);
    }

    // ---- transpose via per-wave LDS tile ----
    // acc[nt][r]: local row16 = g*4+r, local col = nt*16+li
#pragma unroll
    for (int nt = 0; nt < 4; ++nt)
#pragma unroll
      for (int r = 0; r < 4; ++r)
        TT[w][g*4 + r][nt*16 + li] = acc[nt][r];
    asm volatile("s_waitcnt lgkmcnt(0)" ::: "memory");
    __builtin_amdgcn_sched_barrier(0);
    // read back: instr k covers rows 4k+g (4 rows/instr), 16B per lane
#pragma unroll
    for (int k = 0; k < 4; ++k){
      float4 v = *(const float4*)&TT[w][4*k + g][4*li];
      int grow = c*64 + w*16 + 4*k + g;
      *(float4*)&out[(size_t)grow * NITEMS + i0 + 4*li] = v;
    }
    __builtin_amdgcn_sched_barrier(0);
  }
}

// ----------------------------------------------------------------- launch --
extern "C" void kernel_launch(void* const* d_in, const int* in_sizes, int n_in,
                              void* d_out, int out_size, void* d_ws, size_t ws_size,
                              hipStream_t stream){
  const int*   ids      = (const int*)  d_in[0];
  const float* item_emb = (const float*)d_in[1];
  const float* pos_emb  = (const float*)d_in[2];
  const float* ln1g     = (const float*)d_in[3];
  const float* ln1b     = (const float*)d_in[4];
  const float* Wq       = (const float*)d_in[5];
  const float* bq       = (const float*)d_in[6];
  const float* Wk       = (const float*)d_in[7];
  const float* bk       = (const float*)d_in[8];
  const float* Wv       = (const float*)d_in[9];
  const float* bv       = (const float*)d_in[10];
  const float* ln2g     = (const float*)d_in[11];
  const float* ln2b     = (const float*)d_in[12];
  const float* W1       = (const float*)d_in[13];
  const float* b1       = (const float*)d_in[14];
  const float* W2       = (const float*)d_in[15];
  const float* b2       = (const float*)d_in[16];
  const float* lnfg     = (const float*)d_in[17];
  const float* lnfb     = (const float*)d_in[18];
  const float* items    = (const float*)d_in[19];
  float* out  = (float*)d_out;
  float* seq  = (float*)d_ws;                       // 512*64*64 f32 = 8 MB
  float* semb = seq + (size_t)Bsz * Ssz * Dsz;      // 512*64 f32

  k_embed<<<2048, 256, 0, stream>>>(ids, item_emb, pos_emb, seq);
  for (int l = 0; l < 2; ++l)
    k_layer<<<Bsz, 512, 0, stream>>>(seq, ids,
        ln1g + l*64, ln1b + l*64,
        Wq + l*4096, bq + l*64, Wk + l*4096, bk + l*64, Wv + l*4096, bv + l*64,
        ln2g + l*64, ln2b + l*64,
        W1 + l*4096, b1 + l*64, W2 + l*4096, b2 + l*64);
  k_lnf<<<Bsz, 64, 0, stream>>>(seq, lnfg, lnfb, semb);
  k_score<<<3125, 256, 0, stream>>>(semb, items, out);
}

// Round 7
// 225.617 us; speedup vs baseline: 1.0583x; 1.0583x over previous
//
#include <hip/hip_runtime.h>
#include <cstddef>

// SASRec inference. Round 7: k_layer restructured — both transformer blocks
// fused into ONE kernel, 1024 threads (16 waves, 4/SIMD) per block, seq tile
// persistent in LDS across layers. k_score/k_embed/k_lnf unchanged from R6.

#define NITEMS 200000
#define Bsz 512
#define Ssz 64
#define Dsz 64
#define EPSV 1e-3f
#define NEGV (-4294967295.0f)   // -2^32 + 1

typedef __attribute__((ext_vector_type(8))) short short8;   // 8 bf16
typedef __attribute__((ext_vector_type(4))) float f32x4;

static __device__ __forceinline__ float wsum(float v){
#pragma unroll
  for (int o = 32; o > 0; o >>= 1) v += __shfl_xor(v, o, 64);
  return v;
}
static __device__ __forceinline__ float wmax(float v){
#pragma unroll
  for (int o = 32; o > 0; o >>= 1) v = fmaxf(v, __shfl_xor(v, o, 64));
  return v;
}

// bf16 round-to-nearest-even (finite inputs only)
static __device__ __forceinline__ unsigned short f2b(float f){
  unsigned u = __float_as_uint(f);
  unsigned r = u + 0x7fffu + ((u >> 16) & 1u);
  return (unsigned short)(r >> 16);
}
static __device__ __forceinline__ float b2f(unsigned short h){
  return __uint_as_float(((unsigned)h) << 16);
}

// ---------------------------------------------------------------- embed ----
__global__ __launch_bounds__(256) void k_embed(const int* __restrict__ ids,
    const float* __restrict__ item_emb, const float* __restrict__ pos_emb,
    float* __restrict__ seq){
  int e4 = blockIdx.x * 256 + threadIdx.x;      // float4 index over [B*S][16]
  int d4 = e4 & 15, bs = e4 >> 4, s = bs & 63;
  int id = ids[bs];
  float4 r = make_float4(0.f, 0.f, 0.f, 0.f);
  if (id != NITEMS){
    float4 a = ((const float4*)(item_emb + (size_t)id * 64))[d4];
    float4 p = ((const float4*)(pos_emb + s * 64))[d4];
    r = make_float4(a.x + p.x, a.y + p.y, a.z + p.z, a.w + p.w);
  }
  ((float4*)seq)[e4] = r;
}

// ------------------------------------------------------ fused block layers --
// stage: thread t writes its preloaded weight row-slice (k row k0 = t>>4,
// 4 n-cols) into LDS as bf16 hi/lo TRANSPOSED (Wt[n][k]).
static __device__ __forceinline__ void stage_w1024(unsigned short WH[64][72],
    unsigned short WL[64][72], float4 r0, int t){
  __syncthreads();                 // fence previous consumers of WH/WL
  int k0 = t >> 4, n0 = (t & 15) * 4;
  float f0[4] = {r0.x, r0.y, r0.z, r0.w};
#pragma unroll
  for (int j = 0; j < 4; ++j){
    unsigned short h = f2b(f0[j]);
    WH[n0 + j][k0] = h;
    WL[n0 + j][k0] = f2b(f0[j] - b2f(h));
  }
  __syncthreads();
}

// 16x16 output tile of a 64x64 GEMM: A (row-major [m][k] hi/lo) x
// B (transposed [n][k] hi/lo). Wave (qb,cb): rows qb*16..+15, cols cb*16..+15.
// 3-term hi/lo split, fp32 accumulate.
static __device__ __forceinline__ void mm16(
    const unsigned short (*__restrict__ Ah)[72], const unsigned short (*__restrict__ Al)[72],
    const unsigned short (*__restrict__ Bh)[72], const unsigned short (*__restrict__ Bl)[72],
    int qb, int cb, int li, int g, f32x4& acc){
  acc = (f32x4)(0.f);
#pragma unroll
  for (int kc = 0; kc < 2; ++kc){
    short8 ah = *(const short8*)&Ah[qb*16 + li][kc*32 + g*8];
    short8 al = *(const short8*)&Al[qb*16 + li][kc*32 + g*8];
    short8 bh = *(const short8*)&Bh[cb*16 + li][kc*32 + g*8];
    short8 bl = *(const short8*)&Bl[cb*16 + li][kc*32 + g*8];
    acc = __builtin_amdgcn_mfma_f32_16x16x32_bf16(ah, bh, acc, 0, 0, 0);
    acc = __builtin_amdgcn_mfma_f32_16x16x32_bf16(ah, bl, acc, 0, 0, 0);
    acc = __builtin_amdgcn_mfma_f32_16x16x32_bf16(al, bh, acc, 0, 0, 0);
  }
}

__global__ __launch_bounds__(1024) void k_layers(float* __restrict__ seq_g,
    const int* __restrict__ ids,
    const float* __restrict__ ln1g, const float* __restrict__ ln1b,
    const float* __restrict__ Wq, const float* __restrict__ bq,
    const float* __restrict__ Wk, const float* __restrict__ bk,
    const float* __restrict__ Wv, const float* __restrict__ bv,
    const float* __restrict__ ln2g, const float* __restrict__ ln2b,
    const float* __restrict__ W1, const float* __restrict__ b1,
    const float* __restrict__ W2, const float* __restrict__ b2){
  __shared__ float F0[64][68];   // seq -> scores -> x -> layer-out (f32)
  __shared__ float F1[64][68];   // xq (LN1 out) -> x2 (LN2 out) residuals
  // U0: seq -> P ; U1: LN1/LN2 out ; U2: Q -> FFN hidden ; U3: K ; U4: V^T
  __shared__ unsigned short UH[5][64][72], UL[5][64][72];
  __shared__ unsigned short WH[64][72], WL[64][72];
  __shared__ float s_msk[64];

  const int t = threadIdx.x;
  const int lane = t & 63, wid = t >> 6;        // 16 waves
  const int li = lane & 15, g = lane >> 4;
  const int qb = wid & 3, cb = wid >> 2;        // wave tile: rows qb*16, cols cb*16
  const int b = blockIdx.x;
  float* seq_b = seq_g + (size_t)b * Ssz * Dsz;

  // ---- phase 0: load seq -> F0 (f32) + U0 (bf16 h/l); 1 float4/thread ----
  {
    int r = t >> 4, c = (t & 15) * 4;
    float4 v = ((const float4*)seq_b)[t];
    *(float4*)&F0[r][c] = v;
    float f[4] = {v.x, v.y, v.z, v.w};
#pragma unroll
    for (int j = 0; j < 4; ++j){
      unsigned short h = f2b(f[j]);
      UH[0][r][c + j] = h;
      UL[0][r][c + j] = f2b(f[j] - b2f(h));
    }
  }
  if (t < 64) s_msk[t] = (ids[b * Ssz + t] != NITEMS) ? 1.f : 0.f;

  const int k0 = t >> 4, n0 = (t & 15) * 4;

  for (int l = 0; l < 2; ++l){
    // preload this layer's 5 weights (1 float4/thread each); latency hides
    // under the barrier + LN1 below
    float4 w_q = *(const float4*)&Wq[l*4096 + k0*64 + n0];
    float4 w_k = *(const float4*)&Wk[l*4096 + k0*64 + n0];
    float4 w_v = *(const float4*)&Wv[l*4096 + k0*64 + n0];
    float4 w_1 = *(const float4*)&W1[l*4096 + k0*64 + n0];
    float4 w_2 = *(const float4*)&W2[l*4096 + k0*64 + n0];

    __syncthreads();   // fences phase-0 (l=0) or previous layer-out (l=1)

    // ---- LN1: F0 -> F1 (f32) + U1 (bf16 h/l) ----
    for (int r = wid; r < 64; r += 16){
      float x = F0[r][lane];
      float mu = wsum(x) * (1.f / 64.f);
      float dv = x - mu;
      float var = wsum(dv * dv) * (1.f / 64.f);
      float o = dv * (1.f / sqrtf(var + EPSV)) * ln1g[l*64 + lane] + ln1b[l*64 + lane];
      F1[r][lane] = o;
      unsigned short h = f2b(o);
      UH[1][r][lane] = h;
      UL[1][r][lane] = f2b(o - b2f(h));
    }
    // (stage_w1024's leading barrier fences LN1 writes)

    // ---- Q = LN1 @ Wq + bq -> U2 (row-major) ----
    stage_w1024(WH, WL, w_q, t);
    { f32x4 acc; mm16(UH[1], UL[1], WH, WL, qb, cb, li, g, acc);
      int col = cb*16 + li;
      float bb = bq[l*64 + col];
#pragma unroll
      for (int r4 = 0; r4 < 4; ++r4){
        int row = qb*16 + g*4 + r4;
        float qv = acc[r4] + bb;
        unsigned short h = f2b(qv);
        UH[2][row][col] = h; UL[2][row][col] = f2b(qv - b2f(h));
      }
    }
    // ---- K = seq @ Wk + bk -> U3 (row-major [pos][dh]) ----
    stage_w1024(WH, WL, w_k, t);
    { f32x4 acc; mm16(UH[0], UL[0], WH, WL, qb, cb, li, g, acc);
      int col = cb*16 + li;
      float bb = bk[l*64 + col];
#pragma unroll
      for (int r4 = 0; r4 < 4; ++r4){
        int row = qb*16 + g*4 + r4;
        float kv = acc[r4] + bb;
        unsigned short h = f2b(kv);
        UH[3][row][col] = h; UL[3][row][col] = f2b(kv - b2f(h));
      }
    }
    // ---- V = seq @ Wv + bv -> U4 TRANSPOSED (Vt[dh][pos]) ----
    stage_w1024(WH, WL, w_v, t);
    { f32x4 acc; mm16(UH[0], UL[0], WH, WL, qb, cb, li, g, acc);
      int col = cb*16 + li;
      float bb = bv[l*64 + col];
#pragma unroll
      for (int r4 = 0; r4 < 4; ++r4){
        int row = qb*16 + g*4 + r4;
        float vv = acc[r4] + bb;
        unsigned short h = f2b(vv);
        UH[4][col][row] = h; UL[4][col][row] = f2b(vv - b2f(h));
      }
    }
    __syncthreads();

    // ---- scores = Q @ K^T -> F0 (f32) ----
    { f32x4 acc; mm16(UH[2], UL[2], UH[3], UL[3], qb, cb, li, g, acc);
      int col = cb*16 + li;
#pragma unroll
      for (int r4 = 0; r4 < 4; ++r4)
        F0[qb*16 + g*4 + r4][col] = acc[r4];
    }
    __syncthreads();

    // ---- masked softmax: F0 -> U0 (P, bf16 h/l) ----
    for (int r = wid; r < 64; r += 16){
      float raw = F0[r][lane];
      bool valid = (lane <= r) && (s_msk[lane] != 0.f);
      float sc = valid ? raw * 0.125f : NEGV;
      float m = wmax(sc);
      float e = __expf(sc - m);
      float ssumv = wsum(e);
      float p = (e / ssumv) * s_msk[r];
      unsigned short h = f2b(p);
      UH[0][r][lane] = h;
      UL[0][r][lane] = f2b(p - b2f(h));
    }
    __syncthreads();

    // ---- x = P @ V + xq -> F0 (f32) ----
    { f32x4 acc; mm16(UH[0], UL[0], UH[4], UL[4], qb, cb, li, g, acc);
      int col = cb*16 + li;
#pragma unroll
      for (int r4 = 0; r4 < 4; ++r4){
        int row = qb*16 + g*4 + r4;
        F0[row][col] = acc[r4] + F1[row][col];
      }
    }
    __syncthreads();

    // ---- LN2: F0 -> F1 (f32 residual) + U1 (bf16 h/l) ----
    for (int r = wid; r < 64; r += 16){
      float x = F0[r][lane];
      float mu = wsum(x) * (1.f / 64.f);
      float dv = x - mu;
      float var = wsum(dv * dv) * (1.f / 64.f);
      float o = dv * (1.f / sqrtf(var + EPSV)) * ln2g[l*64 + lane] + ln2b[l*64 + lane];
      F1[r][lane] = o;
      unsigned short h = f2b(o);
      UH[1][r][lane] = h;
      UL[1][r][lane] = f2b(o - b2f(h));
    }
    // ---- h = relu(x2 @ W1 + b1) -> U2 ----
    stage_w1024(WH, WL, w_1, t);
    { f32x4 acc; mm16(UH[1], UL[1], WH, WL, qb, cb, li, g, acc);
      int col = cb*16 + li;
      float bb = b1[l*64 + col];
#pragma unroll
      for (int r4 = 0; r4 < 4; ++r4){
        int row = qb*16 + g*4 + r4;
        float hv = fmaxf(acc[r4] + bb, 0.f);
        unsigned short h = f2b(hv);
        UH[2][row][col] = h; UL[2][row][col] = f2b(hv - b2f(h));
      }
    }
    // ---- out = (h @ W2 + b2 + x2) * mask ----
    stage_w1024(WH, WL, w_2, t);
    { f32x4 acc; mm16(UH[2], UL[2], WH, WL, qb, cb, li, g, acc);
      int col = cb*16 + li;
      float bb = b2[l*64 + col];
#pragma unroll
      for (int r4 = 0; r4 < 4; ++r4){
        int row = qb*16 + g*4 + r4;
        float o = (acc[r4] + bb + F1[row][col]) * s_msk[row];
        if (l == 0){
          F0[row][col] = o;                 // state for layer 2
          unsigned short h = f2b(o);
          UH[0][row][col] = h; UL[0][row][col] = f2b(o - b2f(h));
        } else {
          seq_b[row*64 + col] = o;
        }
      }
    }
  }
}

// ------------------------------------------------------------- final LN ----
__global__ __launch_bounds__(64) void k_lnf(const float* __restrict__ seq,
    const float* __restrict__ g, const float* __restrict__ be,
    float* __restrict__ semb){
  int b = blockIdx.x, lane = threadIdx.x;
  float x = seq[(size_t)b * Ssz * Dsz + 63 * 64 + lane];
  float mu = wsum(x) * (1.f / 64.f);
  float dv = x - mu;
  float var = wsum(dv * dv) * (1.f / 64.f);
  semb[b * 64 + lane] = dv * (1.f / sqrtf(var + EPSV)) * g[lane] + be[lane];
}

// --------------------------------------------------------------- scoring ---
// out[b][i] = sum_d E[b][d]*T[i][d], bf16 MFMA hi/lo 3-term split.
// 64-item tile per block (3125 = 200000/64), B-frags in 64 VGPRs.
// C-write: per-wave LDS transpose -> float4 coalesced stores (256B/row-seg).
__global__ __launch_bounds__(256, 4) void k_score(const float* __restrict__ E,
    const float* __restrict__ T, float* __restrict__ out){
  __shared__ float TT[4][16][68];   // per-wave transpose tile (17 KB total)
  const int t = threadIdx.x, lane = t & 63, w = t >> 6;  // 4 waves
  const int li = lane & 15, g = lane >> 4;
  const int i0 = blockIdx.x * 64;

  // B-frags: T rows i0+nt*16+li (always < NITEMS), k = kc*32+g*8..+7
  short8 Bh[8], Bl[8];
#pragma unroll
  for (int nt = 0; nt < 4; ++nt){
    const float4* tp = (const float4*)(T + (size_t)(i0 + nt*16 + li) * 64);
#pragma unroll
    for (int kc = 0; kc < 2; ++kc){
      float4 v0 = tp[kc*8 + g*2];
      float4 v1 = tp[kc*8 + g*2 + 1];
      float f[8] = {v0.x,v0.y,v0.z,v0.w,v1.x,v1.y,v1.z,v1.w};
      short8 h, l;
#pragma unroll
      for (int j = 0; j < 8; ++j){
        unsigned short hh = f2b(f[j]);
        h[j] = (short)hh;
        l[j] = (short)f2b(f[j] - b2f(hh));
      }
      Bh[nt*2 + kc] = h; Bl[nt*2 + kc] = l;
    }
  }

  for (int c = 0; c < 8; ++c){
    int row = c*64 + w*16 + li;
    const float4* ep = (const float4*)(E + (size_t)row * 64);
    short8 Ah[2], Al[2];
#pragma unroll
    for (int kc = 0; kc < 2; ++kc){
      float4 v0 = ep[kc*8 + g*2];
      float4 v1 = ep[kc*8 + g*2 + 1];
      float f[8] = {v0.x,v0.y,v0.z,v0.w,v1.x,v1.y,v1.z,v1.w};
      short8 h, l;
#pragma unroll
      for (int j = 0; j < 8; ++j){
        unsigned short hh = f2b(f[j]);
        h[j] = (short)hh;
        l[j] = (short)f2b(f[j] - b2f(hh));
      }
      Ah[kc] = h; Al[kc] = l;
    }

    f32x4 acc[4];
#pragma unroll
    for (int nt = 0; nt < 4; ++nt) acc[nt] = (f32x4)(0.f);
#pragma unroll
    for (int kc = 0; kc < 2; ++kc){
#pragma unroll
      for (int nt = 0; nt < 4; ++nt)
        acc[nt] = __builtin_amdgcn_mfma_f32_16x16x32_bf16(Ah[kc], Bh[nt*2+kc], acc[nt], 0, 0, 0);
#pragma unroll
      for (int nt = 0; nt < 4; ++nt)
        acc[nt] = __builtin_amdgcn_mfma_f32_16x16x32_bf16(Ah[kc], Bl[nt*2+kc], acc[nt], 0, 0, 0);
#pragma unroll
      for (int nt = 0; nt < 4; ++nt)
        acc[nt] = __builtin_amdgcn_mfma_f32_16x16x32_bf16(Al[kc], Bh[nt*2+kc], acc[nt], 0, 0, 0);
    }

    // ---- transpose via per-wave LDS tile ----
#pragma unroll
    for (int nt = 0; nt < 4; ++nt)
#pragma unroll
      for (int r = 0; r < 4; ++r)
        TT[w][g*4 + r][nt*16 + li] = acc[nt][r];
    asm volatile("s_waitcnt lgkmcnt(0)" ::: "memory");
    __builtin_amdgcn_sched_barrier(0);
#pragma unroll
    for (int k = 0; k < 4; ++k){
      float4 v = *(const float4*)&TT[w][4*k + g][4*li];
      int grow = c*64 + w*16 + 4*k + g;
      *(float4*)&out[(size_t)grow * NITEMS + i0 + 4*li] = v;
    }
    __builtin_amdgcn_sched_barrier(0);
  }
}

// ----------------------------------------------------------------- launch --
extern "C" void kernel_launch(void* const* d_in, const int* in_sizes, int n_in,
                              void* d_out, int out_size, void* d_ws, size_t ws_size,
                              hipStream_t stream){
  const int*   ids      = (const int*)  d_in[0];
  const float* item_emb = (const float*)d_in[1];
  const float* pos_emb  = (const float*)d_in[2];
  const float* ln1g     = (const float*)d_in[3];
  const float* ln1b     = (const float*)d_in[4];
  const float* Wq       = (const float*)d_in[5];
  const float* bq       = (const float*)d_in[6];
  const float* Wk       = (const float*)d_in[7];
  const float* bk       = (const float*)d_in[8];
  const float* Wv       = (const float*)d_in[9];
  const float* bv       = (const float*)d_in[10];
  const float* ln2g     = (const float*)d_in[11];
  const float* ln2b     = (const float*)d_in[12];
  const float* W1       = (const float*)d_in[13];
  const float* b1       = (const float*)d_in[14];
  const float* W2       = (const float*)d_in[15];
  const float* b2       = (const float*)d_in[16];
  const float* lnfg     = (const float*)d_in[17];
  const float* lnfb     = (const float*)d_in[18];
  const float* items    = (const float*)d_in[19];
  float* out  = (float*)d_out;
  float* seq  = (float*)d_ws;                       // 512*64*64 f32 = 8 MB
  float* semb = seq + (size_t)Bsz * Ssz * Dsz;      // 512*64 f32

  k_embed<<<2048, 256, 0, stream>>>(ids, item_emb, pos_emb, seq);
  k_layers<<<Bsz, 1024, 0, stream>>>(seq, ids,
      ln1g, ln1b, Wq, bq, Wk, bk, Wv, bv,
      ln2g, ln2b, W1, b1, W2, b2);
  k_lnf<<<Bsz, 64, 0, stream>>>(seq, lnfg, lnfb, semb);
  k_score<<<3125, 256, 0, stream>>>(semb, items, out);
}